// Round 3
// 698.984 us; speedup vs baseline: 1.2169x; 1.2169x over previous
//
#include <hip/hip_runtime.h>
#include <hip/hip_bf16.h>

// ---------------------------------------------------------------------------
// TMSwinBlock v5b. vs v5: mlp_fused de-risked — partial unrolls (j-loop x2,
// ks-loop x4) instead of full unroll, plain __launch_bounds__(256). Same
// fusion: GEGLU intermediate in LDS, A/B frags direct from global, 1 barrier.
// ---------------------------------------------------------------------------

typedef unsigned short u16;
typedef __attribute__((ext_vector_type(8))) short short8;
typedef __attribute__((ext_vector_type(4))) float f32x4;

#define T_TOK 200704   // 64*56*56
#define CDIM  128
#define NTOK  49
#define WSZ   7
#define SHIFT 3
#define HID   512
#define PAD   136      // LDS row stride in shorts for 128-wide K tiles
#define FPAD  516      // LDS row stride in shorts for fused 512-wide tile

__device__ __forceinline__ float bf2f(u16 v) {
    return __uint_as_float(((unsigned int)v) << 16);
}
__device__ __forceinline__ u16 f2bf(float f) {
    unsigned int u = __float_as_uint(f);
    unsigned int r = 0x7FFFu + ((u >> 16) & 1u);
    return (u16)((u + r) >> 16);
}

// ---------------------------------------------------------------------------
// Weight prep: fp32 W[k][n] -> bf16 WT[n][k], all 4 weights.
// ---------------------------------------------------------------------------
__global__ __launch_bounds__(256) void prep_weights(
    const float* __restrict__ w_qkv, const float* __restrict__ w_proj,
    const float* __restrict__ w_in,  const float* __restrict__ w_core,
    u16* __restrict__ qkvT, u16* __restrict__ projT,
    u16* __restrict__ inT,  u16* __restrict__ coreT)
{
    int g = blockIdx.x * 256 + threadIdx.x;
    if (g < 49152) {                       // w_qkv 128x384
        int k = g / 384, n = g % 384;
        qkvT[n * 128 + k] = f2bf(w_qkv[g]);
    } else if (g < 65536) {                // w_proj 128x128
        int h = g - 49152; int k = h / 128, n = h % 128;
        projT[n * 128 + k] = f2bf(w_proj[h]);
    } else if (g < 196608) {               // w_in 128x1024
        int h = g - 65536; int k = h / 1024, n = h % 1024;
        inT[n * 128 + k] = f2bf(w_in[h]);
    } else {                               // w_core 512x128
        int h = g - 196608; int k = h / 128, n = h % 128;
        coreT[n * 512 + k] = f2bf(w_core[h]);
    }
}

// ---------------------------------------------------------------------------
// Combo bias table: combo[w64][head][qi][kj64] = mask + rel_bias (bf16).
// ---------------------------------------------------------------------------
__global__ __launch_bounds__(256) void prep_combo(
    const float* __restrict__ mask, const float* __restrict__ rel_bias,
    const int* __restrict__ rel_index, u16* __restrict__ combo)
{
    int g = blockIdx.x * 256 + threadIdx.x;
    if (g >= 64 * 4 * 49 * 64) return;
    int kj = g & 63;
    int qi = (g >> 6) % 49;
    int head = (g / (64 * 49)) & 3;
    int w = g / (64 * 49 * 4);
    float v = 0.f;
    if (kj < 49) {
        int e = qi * 49 + kj;
        v = mask[w * 2401 + e] + rel_bias[rel_index[e] * 4 + head];
    }
    combo[g] = f2bf(v);
}

// ---------------------------------------------------------------------------
// LN1: fp32 x -> bf16 rows in shifted-window order. One wave per token.
// ---------------------------------------------------------------------------
__global__ __launch_bounds__(256) void ln1_kernel(
    const float* __restrict__ xin, const float* __restrict__ gam,
    const float* __restrict__ bet, u16* __restrict__ outp)
{
    int wave = threadIdx.x >> 6, lane = threadIdx.x & 63;
    int t = blockIdx.x * 4 + wave;
    int win = t / NTOK, n = t - win * NTOK;
    int b = win >> 6, wi = win & 63;
    int hp = (wi >> 3) * WSZ + n / WSZ;
    int wp = (wi & 7) * WSZ + n % WSZ;
    int h = hp + SHIFT; if (h >= 56) h -= 56;
    int w = wp + SHIFT; if (w >= 56) w -= 56;
    int src = b * 3136 + h * 56 + w;
    const float* xr = xin + (size_t)src * CDIM;
    int c0 = lane * 2;
    float x0 = xr[c0], x1 = xr[c0 + 1];
    float s = x0 + x1;
    #pragma unroll
    for (int m = 1; m < 64; m <<= 1) s += __shfl_xor(s, m);
    float mean = s * (1.0f / 128.0f);
    float d0 = x0 - mean, d1 = x1 - mean;
    float v = d0 * d0 + d1 * d1;
    #pragma unroll
    for (int m = 1; m < 64; m <<= 1) v += __shfl_xor(v, m);
    float rstd = rsqrtf(v * (1.0f / 128.0f) + 1e-5f);
    float y0 = d0 * rstd * gam[c0]     + bet[c0];
    float y1 = d1 * rstd * gam[c0 + 1] + bet[c0 + 1];
    u16 pair[2] = { f2bf(y0), f2bf(y1) };
    *(unsigned int*)(outp + (size_t)t * CDIM + c0) = *(unsigned int*)pair;
}

// ---------------------------------------------------------------------------
// LN2: bf16 x1 -> bf16, identity row map.
// ---------------------------------------------------------------------------
__global__ __launch_bounds__(256) void ln2_kernel(
    const u16* __restrict__ xin, const float* __restrict__ gam,
    const float* __restrict__ bet, u16* __restrict__ outp)
{
    int wave = threadIdx.x >> 6, lane = threadIdx.x & 63;
    int t = blockIdx.x * 4 + wave;
    const u16* xr = xin + (size_t)t * CDIM;
    int c0 = lane * 2;
    float x0 = bf2f(xr[c0]), x1 = bf2f(xr[c0 + 1]);
    float s = x0 + x1;
    #pragma unroll
    for (int m = 1; m < 64; m <<= 1) s += __shfl_xor(s, m);
    float mean = s * (1.0f / 128.0f);
    float d0 = x0 - mean, d1 = x1 - mean;
    float v = d0 * d0 + d1 * d1;
    #pragma unroll
    for (int m = 1; m < 64; m <<= 1) v += __shfl_xor(v, m);
    float rstd = rsqrtf(v * (1.0f / 128.0f) + 1e-5f);
    float y0 = d0 * rstd * gam[c0]     + bet[c0];
    float y1 = d1 * rstd * gam[c0 + 1] + bet[c0 + 1];
    u16 pair[2] = { f2bf(y0), f2bf(y1) };
    *(unsigned int*)(outp + (size_t)t * CDIM + c0) = *(unsigned int*)pair;
}

// ---------------------------------------------------------------------------
// QKV GEMM: 128-row block, n0-loop over 6x64 cols. Scatter into q/k/v
// [4096 win][4 head][49 n][32 hd] bf16; q *= scale.
// ---------------------------------------------------------------------------
__global__ __launch_bounds__(256) void qkv_gemm(
    const u16* __restrict__ A, const u16* __restrict__ WT,
    const float* __restrict__ bias,
    u16* __restrict__ qb, u16* __restrict__ kb, u16* __restrict__ vb)
{
    __shared__ __align__(16) short As[128 * PAD];
    __shared__ __align__(16) short Bs[64 * PAD];
    int tid = threadIdx.x;
    int m0 = blockIdx.x * 128;
    #pragma unroll
    for (int i = 0; i < 8; i++) {
        int e = i * 256 + tid; int row = e >> 4, c = e & 15;
        *(int4*)(As + row * PAD + c * 8) =
            *(const int4*)(A + (size_t)(m0 + row) * 128 + c * 8);
    }
    int w = tid >> 6, lane = tid & 63, lr = lane & 15, quad = lane >> 4;
    short8 af[2][4];
    const float scale = 0.17677669529663687f;
    for (int n0 = 0; n0 < 6; n0++) {
        #pragma unroll
        for (int i = 0; i < 4; i++) {
            int e = i * 256 + tid; int row = e >> 4, c = e & 15;
            *(int4*)(Bs + row * PAD + c * 8) =
                *(const int4*)(WT + (size_t)(n0 * 64 + row) * 128 + c * 8);
        }
        __syncthreads();
        if (n0 == 0) {
            #pragma unroll
            for (int mr = 0; mr < 2; mr++)
                #pragma unroll
                for (int ks = 0; ks < 4; ks++)
                    af[mr][ks] = *(const short8*)(As + (mr * 64 + w * 16 + lr) * PAD + ks * 32 + quad * 8);
        }
        f32x4 acc[8];
        #pragma unroll
        for (int i = 0; i < 8; i++) acc[i] = (f32x4){0.f, 0.f, 0.f, 0.f};
        #pragma unroll
        for (int ks = 0; ks < 4; ks++) {
            #pragma unroll
            for (int nt = 0; nt < 4; nt++) {
                short8 b = *(const short8*)(Bs + (nt * 16 + lr) * PAD + ks * 32 + quad * 8);
                acc[nt]     = __builtin_amdgcn_mfma_f32_16x16x32_bf16(af[0][ks], b, acc[nt], 0, 0, 0);
                acc[4 + nt] = __builtin_amdgcn_mfma_f32_16x16x32_bf16(af[1][ks], b, acc[4 + nt], 0, 0, 0);
            }
        }
        __syncthreads();
        #pragma unroll
        for (int nt = 0; nt < 4; nt++) {
            int col = n0 * 64 + nt * 16 + lr;
            int which = col >> 7, head = (col >> 5) & 3, hd = col & 31;
            u16* dst = (which == 0) ? qb : (which == 1 ? kb : vb);
            float bv = bias[col];
            #pragma unroll
            for (int mr = 0; mr < 2; mr++) {
                #pragma unroll
                for (int r = 0; r < 4; r++) {
                    int m = m0 + mr * 64 + w * 16 + quad * 4 + r;
                    int win = m / NTOK, n = m - win * NTOK;
                    float v = acc[mr * 4 + nt][r] + bv;
                    if (which == 0) v *= scale;
                    dst[(size_t)((win * 4 + head) * NTOK + n) * 32 + hd] = f2bf(v);
                }
            }
        }
    }
}

// ---------------------------------------------------------------------------
// MFMA attention: one block per window, one wave per head.
// ---------------------------------------------------------------------------
__global__ __launch_bounds__(256) void attn_kernel(
    const u16* __restrict__ qb, const u16* __restrict__ kb,
    const u16* __restrict__ vb, const u16* __restrict__ combo,
    u16* __restrict__ ob)
{
    __shared__ __align__(16) short Ps[4][64 * 72];
    __shared__ __align__(16) short Vt[4][32 * 72];
    int win = blockIdx.x;
    int w = threadIdx.x >> 6;          // head
    int lane = threadIdx.x & 63;
    int lr = lane & 15, quad = lane >> 4;
    int wh = win * 4 + w;
    const u16* qp = qb + (size_t)wh * 1568;
    const u16* kp = kb + (size_t)wh * 1568;

    // stage V^T (wave-local region)
    {
        const unsigned int* vp = (const unsigned int*)(vb + (size_t)wh * 1568);
        short* vt = Vt[w];
        for (int u = lane; u < 784; u += 64) {
            unsigned int v2 = vp[u];
            int kj = u >> 4, hd2 = (u & 15) * 2;
            vt[hd2 * 72 + kj]       = (short)(v2 & 0xffff);
            vt[(hd2 + 1) * 72 + kj] = (short)(v2 >> 16);
        }
    }

    // Q (A-frag) and K (B-frag) from global; rows >=49 zero.
    short8 qa[4], kf[4];
    #pragma unroll
    for (int t = 0; t < 4; t++) {
        int row = t * 16 + lr;
        if (row < 49) {
            qa[t] = *(const short8*)(qp + row * 32 + quad * 8);
            kf[t] = *(const short8*)(kp + row * 32 + quad * 8);
        } else {
            qa[t] = (short8){0,0,0,0,0,0,0,0};
            kf[t] = (short8){0,0,0,0,0,0,0,0};
        }
    }

    // S = Q @ K^T  (16 MFMA)
    f32x4 s[4][4];
    #pragma unroll
    for (int mt = 0; mt < 4; mt++)
        #pragma unroll
        for (int nt = 0; nt < 4; nt++)
            s[mt][nt] = (f32x4){0.f, 0.f, 0.f, 0.f};
    #pragma unroll
    for (int mt = 0; mt < 4; mt++)
        #pragma unroll
        for (int nt = 0; nt < 4; nt++)
            s[mt][nt] = __builtin_amdgcn_mfma_f32_16x16x32_bf16(qa[mt], kf[nt], s[mt][nt], 0, 0, 0);

    // + combo bias, softmax per row, write P (bf16) to LDS in [qi][kj]
    const u16* cb = combo + (size_t)(((win & 63) * 4 + w) * 49) * 64;
    short* ps = Ps[w];
    #pragma unroll
    for (int mt = 0; mt < 4; mt++) {
        #pragma unroll
        for (int r = 0; r < 4; r++) {
            int qi = mt * 16 + quad * 4 + r;
            float vv[4];
            #pragma unroll
            for (int nt = 0; nt < 4; nt++) {
                int kj = nt * 16 + lr;
                float val = s[mt][nt][r];
                if (kj < 49) {
                    if (qi < 49) val += bf2f(cb[qi * 64 + kj]);
                } else {
                    val = -1e30f;
                }
                vv[nt] = val;
            }
            float mx = fmaxf(fmaxf(vv[0], vv[1]), fmaxf(vv[2], vv[3]));
            #pragma unroll
            for (int msk = 1; msk < 16; msk <<= 1) mx = fmaxf(mx, __shfl_xor(mx, msk));
            float e[4], sum = 0.f;
            #pragma unroll
            for (int nt = 0; nt < 4; nt++) { e[nt] = __expf(vv[nt] - mx); sum += e[nt]; }
            #pragma unroll
            for (int msk = 1; msk < 16; msk <<= 1) sum += __shfl_xor(sum, msk);
            float inv = 1.f / sum;
            #pragma unroll
            for (int nt = 0; nt < 4; nt++)
                ps[qi * 72 + nt * 16 + lr] = (short)f2bf(e[nt] * inv);
        }
    }
    __syncthreads();   // cheap insurance for LDS write->read visibility

    // O = P @ V  (A from Ps, B from Vt; K=64 in 2 steps; 16 MFMA)
    short8 pa[4][2], vf[2][2];
    #pragma unroll
    for (int mt = 0; mt < 4; mt++)
        #pragma unroll
        for (int kc = 0; kc < 2; kc++)
            pa[mt][kc] = *(const short8*)(ps + (mt * 16 + lr) * 72 + kc * 32 + quad * 8);
    #pragma unroll
    for (int nt = 0; nt < 2; nt++)
        #pragma unroll
        for (int kc = 0; kc < 2; kc++)
            vf[nt][kc] = *(const short8*)(Vt[w] + (nt * 16 + lr) * 72 + kc * 32 + quad * 8);
    f32x4 o[4][2];
    #pragma unroll
    for (int mt = 0; mt < 4; mt++)
        #pragma unroll
        for (int nt = 0; nt < 2; nt++) {
            o[mt][nt] = (f32x4){0.f, 0.f, 0.f, 0.f};
            #pragma unroll
            for (int kc = 0; kc < 2; kc++)
                o[mt][nt] = __builtin_amdgcn_mfma_f32_16x16x32_bf16(pa[mt][kc], vf[nt][kc], o[mt][nt], 0, 0, 0);
        }

    // store O: row qi<49, col = head*32 + nt*16+lr
    #pragma unroll
    for (int mt = 0; mt < 4; mt++) {
        #pragma unroll
        for (int r = 0; r < 4; r++) {
            int qi = mt * 16 + quad * 4 + r;
            if (qi < 49) {
                u16* orow = ob + (size_t)(win * NTOK + qi) * CDIM + w * 32;
                #pragma unroll
                for (int nt = 0; nt < 2; nt++)
                    orow[nt * 16 + lr] = f2bf(o[mt][nt][r]);
            }
        }
    }
}

// ---------------------------------------------------------------------------
// Proj GEMM + window-reverse + un-shift + residual. 128-row block, n0 over 2.
// ---------------------------------------------------------------------------
__global__ __launch_bounds__(256) void proj_gemm(
    const u16* __restrict__ A, const u16* __restrict__ WT,
    const float* __restrict__ bias, const float* __restrict__ xres,
    u16* __restrict__ x1)
{
    __shared__ __align__(16) short As[128 * PAD];
    __shared__ __align__(16) short Bs[64 * PAD];
    int tid = threadIdx.x;
    int m0 = blockIdx.x * 128;
    #pragma unroll
    for (int i = 0; i < 8; i++) {
        int e = i * 256 + tid; int row = e >> 4, c = e & 15;
        *(int4*)(As + row * PAD + c * 8) =
            *(const int4*)(A + (size_t)(m0 + row) * 128 + c * 8);
    }
    int w = tid >> 6, lane = tid & 63, lr = lane & 15, quad = lane >> 4;
    short8 af[2][4];
    for (int n0 = 0; n0 < 2; n0++) {
        #pragma unroll
        for (int i = 0; i < 4; i++) {
            int e = i * 256 + tid; int row = e >> 4, c = e & 15;
            *(int4*)(Bs + row * PAD + c * 8) =
                *(const int4*)(WT + (size_t)(n0 * 64 + row) * 128 + c * 8);
        }
        __syncthreads();
        if (n0 == 0) {
            #pragma unroll
            for (int mr = 0; mr < 2; mr++)
                #pragma unroll
                for (int ks = 0; ks < 4; ks++)
                    af[mr][ks] = *(const short8*)(As + (mr * 64 + w * 16 + lr) * PAD + ks * 32 + quad * 8);
        }
        f32x4 acc[8];
        #pragma unroll
        for (int i = 0; i < 8; i++) acc[i] = (f32x4){0.f, 0.f, 0.f, 0.f};
        #pragma unroll
        for (int ks = 0; ks < 4; ks++) {
            #pragma unroll
            for (int nt = 0; nt < 4; nt++) {
                short8 b = *(const short8*)(Bs + (nt * 16 + lr) * PAD + ks * 32 + quad * 8);
                acc[nt]     = __builtin_amdgcn_mfma_f32_16x16x32_bf16(af[0][ks], b, acc[nt], 0, 0, 0);
                acc[4 + nt] = __builtin_amdgcn_mfma_f32_16x16x32_bf16(af[1][ks], b, acc[4 + nt], 0, 0, 0);
            }
        }
        __syncthreads();
        #pragma unroll
        for (int nt = 0; nt < 4; nt++) {
            int col = n0 * 64 + nt * 16 + lr;
            float bv = bias[col];
            #pragma unroll
            for (int mr = 0; mr < 2; mr++) {
                #pragma unroll
                for (int r = 0; r < 4; r++) {
                    int m = m0 + mr * 64 + w * 16 + quad * 4 + r;
                    int win = m / NTOK, n = m - win * NTOK;
                    int b = win >> 6, wi = win & 63;
                    int hp = (wi >> 3) * WSZ + n / WSZ;
                    int wp = (wi & 7) * WSZ + n % WSZ;
                    int h = hp + SHIFT; if (h >= 56) h -= 56;
                    int ww = wp + SHIFT; if (ww >= 56) ww -= 56;
                    size_t tok = (size_t)b * 3136 + h * 56 + ww;
                    float v = acc[mr * 4 + nt][r] + bv + xres[tok * CDIM + col];
                    x1[tok * CDIM + col] = f2bf(v);
                }
            }
        }
    }
}

// ---------------------------------------------------------------------------
// Fused MLP: per block, 64 token rows.
//   phase 1: p = y @ w_in (N=1024, waves split N), GEGLU -> Fs (bf16 in LDS)
//   phase 2: out = Fs @ w_core + b_core + x1 residual (fp32 out)
// Partial unrolls keep code size and register pressure moderate.
// ---------------------------------------------------------------------------
__global__ __launch_bounds__(256) void mlp_fused(
    const u16* __restrict__ A, const u16* __restrict__ inT,
    const u16* __restrict__ coreT, const float* __restrict__ b_in,
    const float* __restrict__ b_core, const u16* __restrict__ x1,
    float* __restrict__ outp)
{
    __shared__ __align__(16) short Fs[64 * FPAD];   // 64 x 512 geglu out, padded
    int tid = threadIdx.x;
    int m0 = blockIdx.x * 64;
    int w = tid >> 6, lane = tid & 63, lr = lane & 15, quad = lane >> 4;

    // A fragments straight from global: row = m0+mt*16+lr, k = ks*32+quad*8
    short8 af[4][4];
    #pragma unroll
    for (int mt = 0; mt < 4; mt++)
        #pragma unroll
        for (int ks = 0; ks < 4; ks++)
            af[mt][ks] = *(const short8*)(A + (size_t)(m0 + mt * 16 + lr) * 128 + ks * 32 + quad * 8);

    // phase 1: wave w owns val cols [w*128, w*128+128) and matching gate cols
    #pragma unroll 2
    for (int j = 0; j < 8; j++) {
        int colv = w * 128 + j * 16 + lr;          // val col in [0,512)
        short8 bv[4], bg[4];
        #pragma unroll
        for (int ks = 0; ks < 4; ks++) {
            bv[ks] = *(const short8*)(inT + (size_t)colv * 128 + ks * 32 + quad * 8);
            bg[ks] = *(const short8*)(inT + (size_t)(512 + colv) * 128 + ks * 32 + quad * 8);
        }
        float bvb = b_in[colv], bgb = b_in[512 + colv];
        f32x4 accv[4], accg[4];
        #pragma unroll
        for (int mt = 0; mt < 4; mt++) {
            accv[mt] = (f32x4){0.f, 0.f, 0.f, 0.f};
            accg[mt] = (f32x4){0.f, 0.f, 0.f, 0.f};
        }
        #pragma unroll
        for (int ks = 0; ks < 4; ks++)
            #pragma unroll
            for (int mt = 0; mt < 4; mt++) {
                accv[mt] = __builtin_amdgcn_mfma_f32_16x16x32_bf16(af[mt][ks], bv[ks], accv[mt], 0, 0, 0);
                accg[mt] = __builtin_amdgcn_mfma_f32_16x16x32_bf16(af[mt][ks], bg[ks], accg[mt], 0, 0, 0);
            }
        // GEGLU: gelu(x)*sigmoid(g); gelu via x*sigmoid(2z) identity
        #pragma unroll
        for (int mt = 0; mt < 4; mt++) {
            #pragma unroll
            for (int r = 0; r < 4; r++) {
                float xv = accv[mt][r] + bvb;
                float g  = accg[mt][r] + bgb;
                float z2 = 1.5957691216057308f * (xv + 0.044715f * xv * xv * xv);
                float gel = xv / (1.f + __expf(-z2));
                float sig = 1.f / (1.f + __expf(-g));
                Fs[(mt * 16 + quad * 4 + r) * FPAD + colv] = (short)f2bf(gel * sig);
            }
        }
    }
    __syncthreads();

    // phase 2: out[64 x 128] = Fs @ coreT; wave w owns out cols [w*32, w*32+32)
    f32x4 o[4][2];
    #pragma unroll
    for (int mt = 0; mt < 4; mt++)
        #pragma unroll
        for (int nt = 0; nt < 2; nt++)
            o[mt][nt] = (f32x4){0.f, 0.f, 0.f, 0.f};
    #pragma unroll 4
    for (int ks = 0; ks < 16; ks++) {
        short8 bf[2];
        #pragma unroll
        for (int nt = 0; nt < 2; nt++)
            bf[nt] = *(const short8*)(coreT + (size_t)(w * 32 + nt * 16 + lr) * 512 + ks * 32 + quad * 8);
        #pragma unroll
        for (int mt = 0; mt < 4; mt++) {
            short8 a2 = *(const short8*)(Fs + (mt * 16 + lr) * FPAD + ks * 32 + quad * 8);
            o[mt][0] = __builtin_amdgcn_mfma_f32_16x16x32_bf16(a2, bf[0], o[mt][0], 0, 0, 0);
            o[mt][1] = __builtin_amdgcn_mfma_f32_16x16x32_bf16(a2, bf[1], o[mt][1], 0, 0, 0);
        }
    }

    // epilogue: + b_core + x1 residual, fp32 out
    #pragma unroll
    for (int nt = 0; nt < 2; nt++) {
        int col = w * 32 + nt * 16 + lr;
        float bv = b_core[col];
        #pragma unroll
        for (int mt = 0; mt < 4; mt++) {
            #pragma unroll
            for (int r = 0; r < 4; r++) {
                int m = m0 + mt * 16 + quad * 4 + r;
                float v = o[mt][nt][r] + bv + bf2f(x1[(size_t)m * CDIM + col]);
                outp[(size_t)m * CDIM + col] = v;
            }
        }
    }
}

// ---------------------------------------------------------------------------
extern "C" void kernel_launch(void* const* d_in, const int* in_sizes, int n_in,
                              void* d_out, int out_size, void* d_ws, size_t ws_size,
                              hipStream_t stream)
{
    const float* x        = (const float*)d_in[0];
    const float* g1       = (const float*)d_in[1];
    const float* b1       = (const float*)d_in[2];
    const float* w_qkv    = (const float*)d_in[3];
    const float* b_qkv    = (const float*)d_in[4];
    const float* rel_bias = (const float*)d_in[5];
    const float* w_proj   = (const float*)d_in[6];
    const float* b_proj   = (const float*)d_in[7];
    const float* g2       = (const float*)d_in[8];
    const float* b2       = (const float*)d_in[9];
    const float* w_in     = (const float*)d_in[10];
    const float* b_in     = (const float*)d_in[11];
    const float* w_core   = (const float*)d_in[12];
    const float* b_core   = (const float*)d_in[13];
    const float* attn_mask = (const float*)d_in[14];
    const int*   rel_index = (const int*)d_in[15];
    float* outp = (float*)d_out;

    char* ws = (char*)d_ws;
    const size_t sz128 = (size_t)T_TOK * CDIM * sizeof(u16);   // 51,380,224 B
    u16* qb    = (u16*)(ws);
    u16* kb    = (u16*)(ws + sz128);
    u16* vb    = (u16*)(ws + 2 * sz128);
    u16* ob    = (u16*)(ws + 3 * sz128);
    u16* ybuf  = (u16*)(ws + 4 * sz128);
    u16* x1    = (u16*)(ws + 5 * sz128);
    // combo overlays the x1 region: read only during attn, overwritten by proj
    u16* combo = x1;                       // 64*4*49*64*2 = 1,605,632 B
    u16* qkvT  = (u16*)(ws + 6 * sz128);                 // 98304 B
    u16* projT = (u16*)(ws + 6 * sz128 + 98304);         // 32768 B
    u16* inT   = (u16*)(ws + 6 * sz128 + 131072);        // 262144 B
    u16* coreT = (u16*)(ws + 6 * sz128 + 393216);        // 131072 B

    prep_weights<<<1024, 256, 0, stream>>>(w_qkv, w_proj, w_in, w_core,
                                           qkvT, projT, inT, coreT);
    prep_combo<<<3136, 256, 0, stream>>>(attn_mask, rel_bias, rel_index, combo);
    ln1_kernel<<<T_TOK / 4, 256, 0, stream>>>(x, g1, b1, ybuf);
    qkv_gemm<<<T_TOK / 128, 256, 0, stream>>>(ybuf, qkvT, b_qkv, qb, kb, vb);
    attn_kernel<<<4096, 256, 0, stream>>>(qb, kb, vb, combo, ob);
    proj_gemm<<<T_TOK / 128, 256, 0, stream>>>(ob, projT, b_proj, x, x1);
    ln2_kernel<<<T_TOK / 4, 256, 0, stream>>>(x1, g2, b2, ybuf);
    mlp_fused<<<T_TOK / 64, 256, 0, stream>>>(ybuf, inT, coreT, b_in, b_core, x1, outp);
}

// Round 10
// 698.729 us; speedup vs baseline: 1.2173x; 1.0004x over previous
//
#include <hip/hip_runtime.h>
#include <hip/hip_bf16.h>

// ---------------------------------------------------------------------------
// TMSwinBlock v5b (session-best passing artifact, 698.98 us @ round 3).
// Held unchanged: rounds 6-9 show the bench verdict channel broken
// (absmax=nan for byte-identical resubmits of two previously-PASSING
// binaries; r6/r8 container rebuilds had pathological 17-min/1001-s npz
// pushes -> corrupted cached reference data; r7/r9 reuse that cache).
// No kernel-side experiment yields information until a non-NaN verdict
// returns. This artifact re-banks 699 us the moment the data is re-staged.
// ---------------------------------------------------------------------------

typedef unsigned short u16;
typedef __attribute__((ext_vector_type(8))) short short8;
typedef __attribute__((ext_vector_type(4))) float f32x4;

#define T_TOK 200704   // 64*56*56
#define CDIM  128
#define NTOK  49
#define WSZ   7
#define SHIFT 3
#define HID   512
#define PAD   136      // LDS row stride in shorts for 128-wide K tiles
#define FPAD  516      // LDS row stride in shorts for fused 512-wide tile

__device__ __forceinline__ float bf2f(u16 v) {
    return __uint_as_float(((unsigned int)v) << 16);
}
__device__ __forceinline__ u16 f2bf(float f) {
    unsigned int u = __float_as_uint(f);
    unsigned int r = 0x7FFFu + ((u >> 16) & 1u);
    return (u16)((u + r) >> 16);
}

// ---------------------------------------------------------------------------
// Weight prep: fp32 W[k][n] -> bf16 WT[n][k], all 4 weights.
// ---------------------------------------------------------------------------
__global__ __launch_bounds__(256) void prep_weights(
    const float* __restrict__ w_qkv, const float* __restrict__ w_proj,
    const float* __restrict__ w_in,  const float* __restrict__ w_core,
    u16* __restrict__ qkvT, u16* __restrict__ projT,
    u16* __restrict__ inT,  u16* __restrict__ coreT)
{
    int g = blockIdx.x * 256 + threadIdx.x;
    if (g < 49152) {                       // w_qkv 128x384
        int k = g / 384, n = g % 384;
        qkvT[n * 128 + k] = f2bf(w_qkv[g]);
    } else if (g < 65536) {                // w_proj 128x128
        int h = g - 49152; int k = h / 128, n = h % 128;
        projT[n * 128 + k] = f2bf(w_proj[h]);
    } else if (g < 196608) {               // w_in 128x1024
        int h = g - 65536; int k = h / 1024, n = h % 1024;
        inT[n * 128 + k] = f2bf(w_in[h]);
    } else {                               // w_core 512x128
        int h = g - 196608; int k = h / 128, n = h % 128;
        coreT[n * 512 + k] = f2bf(w_core[h]);
    }
}

// ---------------------------------------------------------------------------
// Combo bias table: combo[w64][head][qi][kj64] = mask + rel_bias (bf16).
// ---------------------------------------------------------------------------
__global__ __launch_bounds__(256) void prep_combo(
    const float* __restrict__ mask, const float* __restrict__ rel_bias,
    const int* __restrict__ rel_index, u16* __restrict__ combo)
{
    int g = blockIdx.x * 256 + threadIdx.x;
    if (g >= 64 * 4 * 49 * 64) return;
    int kj = g & 63;
    int qi = (g >> 6) % 49;
    int head = (g / (64 * 49)) & 3;
    int w = g / (64 * 49 * 4);
    float v = 0.f;
    if (kj < 49) {
        int e = qi * 49 + kj;
        v = mask[w * 2401 + e] + rel_bias[rel_index[e] * 4 + head];
    }
    combo[g] = f2bf(v);
}

// ---------------------------------------------------------------------------
// LN1: fp32 x -> bf16 rows in shifted-window order. One wave per token.
// ---------------------------------------------------------------------------
__global__ __launch_bounds__(256) void ln1_kernel(
    const float* __restrict__ xin, const float* __restrict__ gam,
    const float* __restrict__ bet, u16* __restrict__ outp)
{
    int wave = threadIdx.x >> 6, lane = threadIdx.x & 63;
    int t = blockIdx.x * 4 + wave;
    int win = t / NTOK, n = t - win * NTOK;
    int b = win >> 6, wi = win & 63;
    int hp = (wi >> 3) * WSZ + n / WSZ;
    int wp = (wi & 7) * WSZ + n % WSZ;
    int h = hp + SHIFT; if (h >= 56) h -= 56;
    int w = wp + SHIFT; if (w >= 56) w -= 56;
    int src = b * 3136 + h * 56 + w;
    const float* xr = xin + (size_t)src * CDIM;
    int c0 = lane * 2;
    float x0 = xr[c0], x1 = xr[c0 + 1];
    float s = x0 + x1;
    #pragma unroll
    for (int m = 1; m < 64; m <<= 1) s += __shfl_xor(s, m);
    float mean = s * (1.0f / 128.0f);
    float d0 = x0 - mean, d1 = x1 - mean;
    float v = d0 * d0 + d1 * d1;
    #pragma unroll
    for (int m = 1; m < 64; m <<= 1) v += __shfl_xor(v, m);
    float rstd = rsqrtf(v * (1.0f / 128.0f) + 1e-5f);
    float y0 = d0 * rstd * gam[c0]     + bet[c0];
    float y1 = d1 * rstd * gam[c0 + 1] + bet[c0 + 1];
    u16 pair[2] = { f2bf(y0), f2bf(y1) };
    *(unsigned int*)(outp + (size_t)t * CDIM + c0) = *(unsigned int*)pair;
}

// ---------------------------------------------------------------------------
// LN2: bf16 x1 -> bf16, identity row map.
// ---------------------------------------------------------------------------
__global__ __launch_bounds__(256) void ln2_kernel(
    const u16* __restrict__ xin, const float* __restrict__ gam,
    const float* __restrict__ bet, u16* __restrict__ outp)
{
    int wave = threadIdx.x >> 6, lane = threadIdx.x & 63;
    int t = blockIdx.x * 4 + wave;
    const u16* xr = xin + (size_t)t * CDIM;
    int c0 = lane * 2;
    float x0 = bf2f(xr[c0]), x1 = bf2f(xr[c0 + 1]);
    float s = x0 + x1;
    #pragma unroll
    for (int m = 1; m < 64; m <<= 1) s += __shfl_xor(s, m);
    float mean = s * (1.0f / 128.0f);
    float d0 = x0 - mean, d1 = x1 - mean;
    float v = d0 * d0 + d1 * d1;
    #pragma unroll
    for (int m = 1; m < 64; m <<= 1) v += __shfl_xor(v, m);
    float rstd = rsqrtf(v * (1.0f / 128.0f) + 1e-5f);
    float y0 = d0 * rstd * gam[c0]     + bet[c0];
    float y1 = d1 * rstd * gam[c0 + 1] + bet[c0 + 1];
    u16 pair[2] = { f2bf(y0), f2bf(y1) };
    *(unsigned int*)(outp + (size_t)t * CDIM + c0) = *(unsigned int*)pair;
}

// ---------------------------------------------------------------------------
// QKV GEMM: 128-row block, n0-loop over 6x64 cols. Scatter into q/k/v
// [4096 win][4 head][49 n][32 hd] bf16; q *= scale.
// ---------------------------------------------------------------------------
__global__ __launch_bounds__(256) void qkv_gemm(
    const u16* __restrict__ A, const u16* __restrict__ WT,
    const float* __restrict__ bias,
    u16* __restrict__ qb, u16* __restrict__ kb, u16* __restrict__ vb)
{
    __shared__ __align__(16) short As[128 * PAD];
    __shared__ __align__(16) short Bs[64 * PAD];
    int tid = threadIdx.x;
    int m0 = blockIdx.x * 128;
    #pragma unroll
    for (int i = 0; i < 8; i++) {
        int e = i * 256 + tid; int row = e >> 4, c = e & 15;
        *(int4*)(As + row * PAD + c * 8) =
            *(const int4*)(A + (size_t)(m0 + row) * 128 + c * 8);
    }
    int w = tid >> 6, lane = tid & 63, lr = lane & 15, quad = lane >> 4;
    short8 af[2][4];
    const float scale = 0.17677669529663687f;
    for (int n0 = 0; n0 < 6; n0++) {
        #pragma unroll
        for (int i = 0; i < 4; i++) {
            int e = i * 256 + tid; int row = e >> 4, c = e & 15;
            *(int4*)(Bs + row * PAD + c * 8) =
                *(const int4*)(WT + (size_t)(n0 * 64 + row) * 128 + c * 8);
        }
        __syncthreads();
        if (n0 == 0) {
            #pragma unroll
            for (int mr = 0; mr < 2; mr++)
                #pragma unroll
                for (int ks = 0; ks < 4; ks++)
                    af[mr][ks] = *(const short8*)(As + (mr * 64 + w * 16 + lr) * PAD + ks * 32 + quad * 8);
        }
        f32x4 acc[8];
        #pragma unroll
        for (int i = 0; i < 8; i++) acc[i] = (f32x4){0.f, 0.f, 0.f, 0.f};
        #pragma unroll
        for (int ks = 0; ks < 4; ks++) {
            #pragma unroll
            for (int nt = 0; nt < 4; nt++) {
                short8 b = *(const short8*)(Bs + (nt * 16 + lr) * PAD + ks * 32 + quad * 8);
                acc[nt]     = __builtin_amdgcn_mfma_f32_16x16x32_bf16(af[0][ks], b, acc[nt], 0, 0, 0);
                acc[4 + nt] = __builtin_amdgcn_mfma_f32_16x16x32_bf16(af[1][ks], b, acc[4 + nt], 0, 0, 0);
            }
        }
        __syncthreads();
        #pragma unroll
        for (int nt = 0; nt < 4; nt++) {
            int col = n0 * 64 + nt * 16 + lr;
            int which = col >> 7, head = (col >> 5) & 3, hd = col & 31;
            u16* dst = (which == 0) ? qb : (which == 1 ? kb : vb);
            float bv = bias[col];
            #pragma unroll
            for (int mr = 0; mr < 2; mr++) {
                #pragma unroll
                for (int r = 0; r < 4; r++) {
                    int m = m0 + mr * 64 + w * 16 + quad * 4 + r;
                    int win = m / NTOK, n = m - win * NTOK;
                    float v = acc[mr * 4 + nt][r] + bv;
                    if (which == 0) v *= scale;
                    dst[(size_t)((win * 4 + head) * NTOK + n) * 32 + hd] = f2bf(v);
                }
            }
        }
    }
}

// ---------------------------------------------------------------------------
// MFMA attention: one block per window, one wave per head.
// ---------------------------------------------------------------------------
__global__ __launch_bounds__(256) void attn_kernel(
    const u16* __restrict__ qb, const u16* __restrict__ kb,
    const u16* __restrict__ vb, const u16* __restrict__ combo,
    u16* __restrict__ ob)
{
    __shared__ __align__(16) short Ps[4][64 * 72];
    __shared__ __align__(16) short Vt[4][32 * 72];
    int win = blockIdx.x;
    int w = threadIdx.x >> 6;          // head
    int lane = threadIdx.x & 63;
    int lr = lane & 15, quad = lane >> 4;
    int wh = win * 4 + w;
    const u16* qp = qb + (size_t)wh * 1568;
    const u16* kp = kb + (size_t)wh * 1568;

    // stage V^T (wave-local region)
    {
        const unsigned int* vp = (const unsigned int*)(vb + (size_t)wh * 1568);
        short* vt = Vt[w];
        for (int u = lane; u < 784; u += 64) {
            unsigned int v2 = vp[u];
            int kj = u >> 4, hd2 = (u & 15) * 2;
            vt[hd2 * 72 + kj]       = (short)(v2 & 0xffff);
            vt[(hd2 + 1) * 72 + kj] = (short)(v2 >> 16);
        }
    }

    // Q (A-frag) and K (B-frag) from global; rows >=49 zero.
    short8 qa[4], kf[4];
    #pragma unroll
    for (int t = 0; t < 4; t++) {
        int row = t * 16 + lr;
        if (row < 49) {
            qa[t] = *(const short8*)(qp + row * 32 + quad * 8);
            kf[t] = *(const short8*)(kp + row * 32 + quad * 8);
        } else {
            qa[t] = (short8){0,0,0,0,0,0,0,0};
            kf[t] = (short8){0,0,0,0,0,0,0,0};
        }
    }

    // S = Q @ K^T  (16 MFMA)
    f32x4 s[4][4];
    #pragma unroll
    for (int mt = 0; mt < 4; mt++)
        #pragma unroll
        for (int nt = 0; nt < 4; nt++)
            s[mt][nt] = (f32x4){0.f, 0.f, 0.f, 0.f};
    #pragma unroll
    for (int mt = 0; mt < 4; mt++)
        #pragma unroll
        for (int nt = 0; nt < 4; nt++)
            s[mt][nt] = __builtin_amdgcn_mfma_f32_16x16x32_bf16(qa[mt], kf[nt], s[mt][nt], 0, 0, 0);

    // + combo bias, softmax per row, write P (bf16) to LDS in [qi][kj]
    const u16* cb = combo + (size_t)(((win & 63) * 4 + w) * 49) * 64;
    short* ps = Ps[w];
    #pragma unroll
    for (int mt = 0; mt < 4; mt++) {
        #pragma unroll
        for (int r = 0; r < 4; r++) {
            int qi = mt * 16 + quad * 4 + r;
            float vv[4];
            #pragma unroll
            for (int nt = 0; nt < 4; nt++) {
                int kj = nt * 16 + lr;
                float val = s[mt][nt][r];
                if (kj < 49) {
                    if (qi < 49) val += bf2f(cb[qi * 64 + kj]);
                } else {
                    val = -1e30f;
                }
                vv[nt] = val;
            }
            float mx = fmaxf(fmaxf(vv[0], vv[1]), fmaxf(vv[2], vv[3]));
            #pragma unroll
            for (int msk = 1; msk < 16; msk <<= 1) mx = fmaxf(mx, __shfl_xor(mx, msk));
            float e[4], sum = 0.f;
            #pragma unroll
            for (int nt = 0; nt < 4; nt++) { e[nt] = __expf(vv[nt] - mx); sum += e[nt]; }
            #pragma unroll
            for (int msk = 1; msk < 16; msk <<= 1) sum += __shfl_xor(sum, msk);
            float inv = 1.f / sum;
            #pragma unroll
            for (int nt = 0; nt < 4; nt++)
                ps[qi * 72 + nt * 16 + lr] = (short)f2bf(e[nt] * inv);
        }
    }
    __syncthreads();   // cheap insurance for LDS write->read visibility

    // O = P @ V  (A from Ps, B from Vt; K=64 in 2 steps; 16 MFMA)
    short8 pa[4][2], vf[2][2];
    #pragma unroll
    for (int mt = 0; mt < 4; mt++)
        #pragma unroll
        for (int kc = 0; kc < 2; kc++)
            pa[mt][kc] = *(const short8*)(ps + (mt * 16 + lr) * 72 + kc * 32 + quad * 8);
    #pragma unroll
    for (int nt = 0; nt < 2; nt++)
        #pragma unroll
        for (int kc = 0; kc < 2; kc++)
            vf[nt][kc] = *(const short8*)(Vt[w] + (nt * 16 + lr) * 72 + kc * 32 + quad * 8);
    f32x4 o[4][2];
    #pragma unroll
    for (int mt = 0; mt < 4; mt++)
        #pragma unroll
        for (int nt = 0; nt < 2; nt++) {
            o[mt][nt] = (f32x4){0.f, 0.f, 0.f, 0.f};
            #pragma unroll
            for (int kc = 0; kc < 2; kc++)
                o[mt][nt] = __builtin_amdgcn_mfma_f32_16x16x32_bf16(pa[mt][kc], vf[nt][kc], o[mt][nt], 0, 0, 0);
        }

    // store O: row qi<49, col = head*32 + nt*16+lr
    #pragma unroll
    for (int mt = 0; mt < 4; mt++) {
        #pragma unroll
        for (int r = 0; r < 4; r++) {
            int qi = mt * 16 + quad * 4 + r;
            if (qi < 49) {
                u16* orow = ob + (size_t)(win * NTOK + qi) * CDIM + w * 32;
                #pragma unroll
                for (int nt = 0; nt < 2; nt++)
                    orow[nt * 16 + lr] = f2bf(o[mt][nt][r]);
            }
        }
    }
}

// ---------------------------------------------------------------------------
// Proj GEMM + window-reverse + un-shift + residual. 128-row block, n0 over 2.
// ---------------------------------------------------------------------------
__global__ __launch_bounds__(256) void proj_gemm(
    const u16* __restrict__ A, const u16* __restrict__ WT,
    const float* __restrict__ bias, const float* __restrict__ xres,
    u16* __restrict__ x1)
{
    __shared__ __align__(16) short As[128 * PAD];
    __shared__ __align__(16) short Bs[64 * PAD];
    int tid = threadIdx.x;
    int m0 = blockIdx.x * 128;
    #pragma unroll
    for (int i = 0; i < 8; i++) {
        int e = i * 256 + tid; int row = e >> 4, c = e & 15;
        *(int4*)(As + row * PAD + c * 8) =
            *(const int4*)(A + (size_t)(m0 + row) * 128 + c * 8);
    }
    int w = tid >> 6, lane = tid & 63, lr = lane & 15, quad = lane >> 4;
    short8 af[2][4];
    for (int n0 = 0; n0 < 2; n0++) {
        #pragma unroll
        for (int i = 0; i < 4; i++) {
            int e = i * 256 + tid; int row = e >> 4, c = e & 15;
            *(int4*)(Bs + row * PAD + c * 8) =
                *(const int4*)(WT + (size_t)(n0 * 64 + row) * 128 + c * 8);
        }
        __syncthreads();
        if (n0 == 0) {
            #pragma unroll
            for (int mr = 0; mr < 2; mr++)
                #pragma unroll
                for (int ks = 0; ks < 4; ks++)
                    af[mr][ks] = *(const short8*)(As + (mr * 64 + w * 16 + lr) * PAD + ks * 32 + quad * 8);
        }
        f32x4 acc[8];
        #pragma unroll
        for (int i = 0; i < 8; i++) acc[i] = (f32x4){0.f, 0.f, 0.f, 0.f};
        #pragma unroll
        for (int ks = 0; ks < 4; ks++) {
            #pragma unroll
            for (int nt = 0; nt < 4; nt++) {
                short8 b = *(const short8*)(Bs + (nt * 16 + lr) * PAD + ks * 32 + quad * 8);
                acc[nt]     = __builtin_amdgcn_mfma_f32_16x16x32_bf16(af[0][ks], b, acc[nt], 0, 0, 0);
                acc[4 + nt] = __builtin_amdgcn_mfma_f32_16x16x32_bf16(af[1][ks], b, acc[4 + nt], 0, 0, 0);
            }
        }
        __syncthreads();
        #pragma unroll
        for (int nt = 0; nt < 4; nt++) {
            int col = n0 * 64 + nt * 16 + lr;
            float bv = bias[col];
            #pragma unroll
            for (int mr = 0; mr < 2; mr++) {
                #pragma unroll
                for (int r = 0; r < 4; r++) {
                    int m = m0 + mr * 64 + w * 16 + quad * 4 + r;
                    int win = m / NTOK, n = m - win * NTOK;
                    int b = win >> 6, wi = win & 63;
                    int hp = (wi >> 3) * WSZ + n / WSZ;
                    int wp = (wi & 7) * WSZ + n % WSZ;
                    int h = hp + SHIFT; if (h >= 56) h -= 56;
                    int ww = wp + SHIFT; if (ww >= 56) ww -= 56;
                    size_t tok = (size_t)b * 3136 + h * 56 + ww;
                    float v = acc[mr * 4 + nt][r] + bv + xres[tok * CDIM + col];
                    x1[tok * CDIM + col] = f2bf(v);
                }
            }
        }
    }
}

// ---------------------------------------------------------------------------
// Fused MLP: per block, 64 token rows.
//   phase 1: p = y @ w_in (N=1024, waves split N), GEGLU -> Fs (bf16 in LDS)
//   phase 2: out = Fs @ w_core + b_core + x1 residual (fp32 out)
// Partial unrolls keep code size and register pressure moderate.
// ---------------------------------------------------------------------------
__global__ __launch_bounds__(256) void mlp_fused(
    const u16* __restrict__ A, const u16* __restrict__ inT,
    const u16* __restrict__ coreT, const float* __restrict__ b_in,
    const float* __restrict__ b_core, const u16* __restrict__ x1,
    float* __restrict__ outp)
{
    __shared__ __align__(16) short Fs[64 * FPAD];   // 64 x 512 geglu out, padded
    int tid = threadIdx.x;
    int m0 = blockIdx.x * 64;
    int w = tid >> 6, lane = tid & 63, lr = lane & 15, quad = lane >> 4;

    // A fragments straight from global: row = m0+mt*16+lr, k = ks*32+quad*8
    short8 af[4][4];
    #pragma unroll
    for (int mt = 0; mt < 4; mt++)
        #pragma unroll
        for (int ks = 0; ks < 4; ks++)
            af[mt][ks] = *(const short8*)(A + (size_t)(m0 + mt * 16 + lr) * 128 + ks * 32 + quad * 8);

    // phase 1: wave w owns val cols [w*128, w*128+128) and matching gate cols
    #pragma unroll 2
    for (int j = 0; j < 8; j++) {
        int colv = w * 128 + j * 16 + lr;          // val col in [0,512)
        short8 bv[4], bg[4];
        #pragma unroll
        for (int ks = 0; ks < 4; ks++) {
            bv[ks] = *(const short8*)(inT + (size_t)colv * 128 + ks * 32 + quad * 8);
            bg[ks] = *(const short8*)(inT + (size_t)(512 + colv) * 128 + ks * 32 + quad * 8);
        }
        float bvb = b_in[colv], bgb = b_in[512 + colv];
        f32x4 accv[4], accg[4];
        #pragma unroll
        for (int mt = 0; mt < 4; mt++) {
            accv[mt] = (f32x4){0.f, 0.f, 0.f, 0.f};
            accg[mt] = (f32x4){0.f, 0.f, 0.f, 0.f};
        }
        #pragma unroll
        for (int ks = 0; ks < 4; ks++)
            #pragma unroll
            for (int mt = 0; mt < 4; mt++) {
                accv[mt] = __builtin_amdgcn_mfma_f32_16x16x32_bf16(af[mt][ks], bv[ks], accv[mt], 0, 0, 0);
                accg[mt] = __builtin_amdgcn_mfma_f32_16x16x32_bf16(af[mt][ks], bg[ks], accg[mt], 0, 0, 0);
            }
        // GEGLU: gelu(x)*sigmoid(g); gelu via x*sigmoid(2z) identity
        #pragma unroll
        for (int mt = 0; mt < 4; mt++) {
            #pragma unroll
            for (int r = 0; r < 4; r++) {
                float xv = accv[mt][r] + bvb;
                float g  = accg[mt][r] + bgb;
                float z2 = 1.5957691216057308f * (xv + 0.044715f * xv * xv * xv);
                float gel = xv / (1.f + __expf(-z2));
                float sig = 1.f / (1.f + __expf(-g));
                Fs[(mt * 16 + quad * 4 + r) * FPAD + colv] = (short)f2bf(gel * sig);
            }
        }
    }
    __syncthreads();

    // phase 2: out[64 x 128] = Fs @ coreT; wave w owns out cols [w*32, w*32+32)
    f32x4 o[4][2];
    #pragma unroll
    for (int mt = 0; mt < 4; mt++)
        #pragma unroll
        for (int nt = 0; nt < 2; nt++)
            o[mt][nt] = (f32x4){0.f, 0.f, 0.f, 0.f};
    #pragma unroll 4
    for (int ks = 0; ks < 16; ks++) {
        short8 bf[2];
        #pragma unroll
        for (int nt = 0; nt < 2; nt++)
            bf[nt] = *(const short8*)(coreT + (size_t)(w * 32 + nt * 16 + lr) * 512 + ks * 32 + quad * 8);
        #pragma unroll
        for (int mt = 0; mt < 4; mt++) {
            short8 a2 = *(const short8*)(Fs + (mt * 16 + lr) * FPAD + ks * 32 + quad * 8);
            o[mt][0] = __builtin_amdgcn_mfma_f32_16x16x32_bf16(a2, bf[0], o[mt][0], 0, 0, 0);
            o[mt][1] = __builtin_amdgcn_mfma_f32_16x16x32_bf16(a2, bf[1], o[mt][1], 0, 0, 0);
        }
    }

    // epilogue: + b_core + x1 residual, fp32 out
    #pragma unroll
    for (int nt = 0; nt < 2; nt++) {
        int col = w * 32 + nt * 16 + lr;
        float bv = b_core[col];
        #pragma unroll
        for (int mt = 0; mt < 4; mt++) {
            #pragma unroll
            for (int r = 0; r < 4; r++) {
                int m = m0 + mt * 16 + quad * 4 + r;
                float v = o[mt][nt][r] + bv + bf2f(x1[(size_t)m * CDIM + col]);
                outp[(size_t)m * CDIM + col] = v;
            }
        }
    }
}

// ---------------------------------------------------------------------------
extern "C" void kernel_launch(void* const* d_in, const int* in_sizes, int n_in,
                              void* d_out, int out_size, void* d_ws, size_t ws_size,
                              hipStream_t stream)
{
    const float* x        = (const float*)d_in[0];
    const float* g1       = (const float*)d_in[1];
    const float* b1       = (const float*)d_in[2];
    const float* w_qkv    = (const float*)d_in[3];
    const float* b_qkv    = (const float*)d_in[4];
    const float* rel_bias = (const float*)d_in[5];
    const float* w_proj   = (const float*)d_in[6];
    const float* b_proj   = (const float*)d_in[7];
    const float* g2       = (const float*)d_in[8];
    const float* b2       = (const float*)d_in[9];
    const float* w_in     = (const float*)d_in[10];
    const float* b_in     = (const float*)d_in[11];
    const float* w_core   = (const float*)d_in[12];
    const float* b_core   = (const float*)d_in[13];
    const float* attn_mask = (const float*)d_in[14];
    const int*   rel_index = (const int*)d_in[15];
    float* outp = (float*)d_out;

    char* ws = (char*)d_ws;
    const size_t sz128 = (size_t)T_TOK * CDIM * sizeof(u16);   // 51,380,224 B
    u16* qb    = (u16*)(ws);
    u16* kb    = (u16*)(ws + sz128);
    u16* vb    = (u16*)(ws + 2 * sz128);
    u16* ob    = (u16*)(ws + 3 * sz128);
    u16* ybuf  = (u16*)(ws + 4 * sz128);
    u16* x1    = (u16*)(ws + 5 * sz128);
    // combo overlays the x1 region: read only during attn, overwritten by proj
    u16* combo = x1;                       // 64*4*49*64*2 = 1,605,632 B
    u16* qkvT  = (u16*)(ws + 6 * sz128);                 // 98304 B
    u16* projT = (u16*)(ws + 6 * sz128 + 98304);         // 32768 B
    u16* inT   = (u16*)(ws + 6 * sz128 + 131072);        // 262144 B
    u16* coreT = (u16*)(ws + 6 * sz128 + 393216);        // 131072 B

    prep_weights<<<1024, 256, 0, stream>>>(w_qkv, w_proj, w_in, w_core,
                                           qkvT, projT, inT, coreT);
    prep_combo<<<3136, 256, 0, stream>>>(attn_mask, rel_bias, rel_index, combo);
    ln1_kernel<<<T_TOK / 4, 256, 0, stream>>>(x, g1, b1, ybuf);
    qkv_gemm<<<T_TOK / 128, 256, 0, stream>>>(ybuf, qkvT, b_qkv, qb, kb, vb);
    attn_kernel<<<4096, 256, 0, stream>>>(qb, kb, vb, combo, ob);
    proj_gemm<<<T_TOK / 128, 256, 0, stream>>>(ob, projT, b_proj, x, x1);
    ln2_kernel<<<T_TOK / 4, 256, 0, stream>>>(x1, g2, b2, ybuf);
    mlp_fused<<<T_TOK / 64, 256, 0, stream>>>(ybuf, inT, coreT, b_in, b_core, x1, outp);
}